// Round 3
// baseline (764.976 us; speedup 1.0000x reference)
//
#include <hip/hip_runtime.h>

#define BATCH 16384

typedef unsigned short u16;
typedef __attribute__((ext_vector_type(8))) short short8;
typedef __attribute__((ext_vector_type(4))) short short4v;
typedef __attribute__((ext_vector_type(4))) float f32x4;

// ---------- bf16 split helpers ----------
__device__ __forceinline__ u16 f2bf(float x) {
    union { float f; unsigned int u; } a; a.f = x;
    unsigned int r = a.u + 0x7fffu + ((a.u >> 16) & 1u);   // RTN-even
    return (u16)(r >> 16);
}
__device__ __forceinline__ float bf2f(u16 h) {
    union { unsigned int u; float f; } a; a.u = ((unsigned int)h) << 16;
    return a.f;
}

// ================= weight pre-pack kernels =================
// MFMA fragment pack: P[(v*KG + (k>>3))*N + n][k&7] so one fragment
// (8 consecutive k at fixed n) is a contiguous 16B load.
// prep_w1: K=64 rows only (u-row 64 handled in-kernel), PRE-MASKED by the
// parent mask m_v[k] = (G[k][v] > 0) — strictly-upper G means masked-out
// columns are exactly the not-yet-computed ones, so A needs no masking.
__global__ void prep_w1(const float* __restrict__ W1, const int* __restrict__ G,
                        u16* __restrict__ Ph, u16* __restrict__ Pl) {
    int idx = blockIdx.x * 256 + threadIdx.x;   // 64*64*256 exactly
    int n = idx & 255;
    int k = (idx >> 8) & 63;
    int v = idx >> 14;
    float w = (G[k * 64 + v] > 0) ? W1[((size_t)v * 65 + k) * 256 + n] : 0.0f;
    u16 h = f2bf(w);
    u16 l = f2bf(w - bf2f(h));
    size_t o = (((size_t)(v * 8 + (k >> 3)) * 256 + n) << 3) + (k & 7);
    Ph[o] = h; Pl[o] = l;
}
__global__ void prep_w2(const float* __restrict__ W2, u16* __restrict__ Ph,
                        u16* __restrict__ Pl) {
    int idx = blockIdx.x * 256 + threadIdx.x;   // 64*256*128 exactly
    int n = idx & 127;
    int k = (idx >> 7) & 255;
    int v = idx >> 15;
    float w = W2[((size_t)v * 256 + k) * 128 + n];
    u16 h = f2bf(w);
    u16 l = f2bf(w - bf2f(h));
    size_t o = (((size_t)(v * 32 + (k >> 3)) * 128 + n) << 3) + (k & 7);
    Ph[o] = h; Pl[o] = l;
}

// ================= persistent fused kernel =================
// One block = 64 batch rows, loops over all 64 variables with the Y-tile
// resident in LDS as bf16 hi/lo. No inter-block communication at all.
#define AST   72     // Y-tile LDS stride (elems): 64 + pad, 144B (16B mult)
#define H1ST  264    // h1 LDS stride: 256 + pad, 528B (16B mult)

__global__ __launch_bounds__(512, 1)
void sen_fused(const float* __restrict__ U,
               const u16* __restrict__ P1h, const u16* __restrict__ P1l,
               const u16* __restrict__ P2h, const u16* __restrict__ P2l,
               const float* __restrict__ W1, const float* __restrict__ b1,
               const float* __restrict__ b2, const float* __restrict__ W3,
               const float* __restrict__ b3, float* __restrict__ Y)
{
    __shared__ __attribute__((aligned(16))) u16 Ah[64 * AST];
    __shared__ __attribute__((aligned(16))) u16 Al[64 * AST];
    __shared__ __attribute__((aligned(16))) u16 h1h[64 * H1ST];
    __shared__ __attribute__((aligned(16))) u16 h1l[64 * H1ST];
    __shared__ float u_lds[64];
    __shared__ float yp[4][64];

    const int tid  = threadIdx.x;
    const int row0 = blockIdx.x * 64;

    // zero-init Y tile (garbage NaN x zero-weight would still be NaN in MFMA)
    {
        short8 z = {0,0,0,0,0,0,0,0};
        for (int i = tid; i < (64 * AST) / 8; i += 512) {
            *(short8*)&Ah[i * 8] = z;
            *(short8*)&Al[i * 8] = z;
        }
    }
    if (tid < 64) u_lds[tid] = U[(size_t)(row0 + tid) * 64];   // u column for v=0
    __syncthreads();

    const int w  = tid >> 6, l = tid & 63;
    const int mg = w & 3, nb = w >> 2;   // layer1 (swapped) roles: dim-group, browhalf
    const int rh = nb,    cg = mg;       // layer2 roles: row-half, col-group
    const int lr = l & 15, lk = l >> 4;

    for (int v = 0; v < 64; ++v) {
        // ---- prefetch per-step scalars/vectors (latency hides under MFMAs) ----
        f32x4 b1v[4], w64v[4];
        #pragma unroll
        for (int ni = 0; ni < 4; ++ni) {
            b1v[ni]  = *(const f32x4*)(b1 + v * 256 + mg * 64 + ni * 16 + lk * 4);
            w64v[ni] = *(const f32x4*)(W1 + ((size_t)v * 65 + 64) * 256 + mg * 64 + ni * 16 + lk * 4);
        }
        float b2c[2], w3c[2];
        #pragma unroll
        for (int ni = 0; ni < 2; ++ni) {
            b2c[ni] = b2[v * 128 + cg * 32 + ni * 16 + lr];
            w3c[ni] = W3[v * 128 + cg * 32 + ni * 16 + lr];
        }
        const float u_c[2] = { u_lds[nb * 32 + lr], u_lds[nb * 32 + 16 + lr] };

        // ======== Layer 1 (operand-swapped): h1t[dim][brow] = W1t @ Yt ========
        // wave covers dims mg*64..+63 (4 ni) x brows nb*32..+31 (2 nj), K=64
        f32x4 acc1[2][4];
        #pragma unroll
        for (int nj = 0; nj < 2; ++nj)
            #pragma unroll
            for (int ni = 0; ni < 4; ++ni) acc1[nj][ni] = (f32x4){0.f, 0.f, 0.f, 0.f};

        #pragma unroll
        for (int kt = 0; kt < 2; ++kt) {
            short8 Yfh[2], Yfl[2];
            #pragma unroll
            for (int nj = 0; nj < 2; ++nj) {
                const int brow = nb * 32 + nj * 16 + lr;
                Yfh[nj] = *(const short8*)&Ah[brow * AST + kt * 32 + lk * 8];
                Yfl[nj] = *(const short8*)&Al[brow * AST + kt * 32 + lk * 8];
            }
            #pragma unroll
            for (int ni = 0; ni < 4; ++ni) {
                const size_t off = (((size_t)(v * 8 + kt * 4 + lk) * 256) + mg * 64 + ni * 16 + lr) << 3;
                const short8 Wh = *(const short8*)&P1h[off];
                const short8 Wl = *(const short8*)&P1l[off];
                #pragma unroll
                for (int nj = 0; nj < 2; ++nj) {
                    acc1[nj][ni] = __builtin_amdgcn_mfma_f32_16x16x32_bf16(Wh, Yfh[nj], acc1[nj][ni], 0, 0, 0);
                    acc1[nj][ni] = __builtin_amdgcn_mfma_f32_16x16x32_bf16(Wh, Yfl[nj], acc1[nj][ni], 0, 0, 0);
                    acc1[nj][ni] = __builtin_amdgcn_mfma_f32_16x16x32_bf16(Wl, Yfh[nj], acc1[nj][ni], 0, 0, 0);
                }
            }
        }
        // epilogue: + bias + u*W1[64,:]  (rank-1 u-term in fp32 VALU), relu,
        // hi/lo split, 4-consecutive-dim packed b64 stores into h1[brow][dim]
        #pragma unroll
        for (int nj = 0; nj < 2; ++nj) {
            const int brow = nb * 32 + nj * 16 + lr;
            #pragma unroll
            for (int ni = 0; ni < 4; ++ni) {
                short4v ph, pl;
                #pragma unroll
                for (int r = 0; r < 4; ++r) {
                    float x = acc1[nj][ni][r] + b1v[ni][r] + u_c[nj] * w64v[ni][r];
                    x = fmaxf(x, 0.0f);
                    u16 h = f2bf(x);
                    ph[r] = (short)h;
                    pl[r] = (short)f2bf(x - bf2f(h));
                }
                const int a = brow * H1ST + mg * 64 + ni * 16 + lk * 4;
                *(short4v*)&h1h[a] = ph;
                *(short4v*)&h1l[a] = pl;
            }
        }
        __syncthreads();

        // ======== Layer 2 + fused layer 3: h2 = relu(h1@W2+b2); y = h2·w3 ========
        f32x4 acc2[2][2];
        #pragma unroll
        for (int mi = 0; mi < 2; ++mi)
            #pragma unroll
            for (int ni = 0; ni < 2; ++ni) acc2[mi][ni] = (f32x4){0.f, 0.f, 0.f, 0.f};

        #pragma unroll
        for (int kt = 0; kt < 8; ++kt) {
            short8 Hfh[2], Hfl[2];
            #pragma unroll
            for (int mi = 0; mi < 2; ++mi) {
                const int row = rh * 32 + mi * 16 + lr;
                Hfh[mi] = *(const short8*)&h1h[row * H1ST + kt * 32 + lk * 8];
                Hfl[mi] = *(const short8*)&h1l[row * H1ST + kt * 32 + lk * 8];
            }
            #pragma unroll
            for (int ni = 0; ni < 2; ++ni) {
                const size_t off = (((size_t)(v * 32 + kt * 4 + lk) * 128) + cg * 32 + ni * 16 + lr) << 3;
                const short8 Bh = *(const short8*)&P2h[off];
                const short8 Bl = *(const short8*)&P2l[off];
                #pragma unroll
                for (int mi = 0; mi < 2; ++mi) {
                    acc2[mi][ni] = __builtin_amdgcn_mfma_f32_16x16x32_bf16(Hfh[mi], Bh, acc2[mi][ni], 0, 0, 0);
                    acc2[mi][ni] = __builtin_amdgcn_mfma_f32_16x16x32_bf16(Hfh[mi], Bl, acc2[mi][ni], 0, 0, 0);
                    acc2[mi][ni] = __builtin_amdgcn_mfma_f32_16x16x32_bf16(Hfl[mi], Bh, acc2[mi][ni], 0, 0, 0);
                }
            }
        }
        // layer3 in-register: partial y per col-group, shfl-reduce over lr
        #pragma unroll
        for (int mi = 0; mi < 2; ++mi)
            #pragma unroll
            for (int r = 0; r < 4; ++r) {
                float s = fmaxf(acc2[mi][0][r] + b2c[0], 0.0f) * w3c[0]
                        + fmaxf(acc2[mi][1][r] + b2c[1], 0.0f) * w3c[1];
                s += __shfl_xor(s, 1);
                s += __shfl_xor(s, 2);
                s += __shfl_xor(s, 4);
                s += __shfl_xor(s, 8);
                if (lr == 0) yp[cg][rh * 32 + mi * 16 + lk * 4 + r] = s;
            }
        __syncthreads();

        // ---- y column -> Y tile (bf16 hi/lo), prefetch next u column ----
        if (tid < 64) {
            float y = yp[0][tid] + yp[1][tid] + yp[2][tid] + yp[3][tid] + b3[v];
            u16 h = f2bf(y);
            Ah[tid * AST + v] = h;
            Al[tid * AST + v] = f2bf(y - bf2f(h));
            if (v < 63) u_lds[tid] = U[(size_t)(row0 + tid) * 64 + v + 1];
        }
        __syncthreads();
    }

    // ---- final coalesced store of the whole tile (hi+lo reconstruct) ----
    {
        const int row = tid >> 3, c8 = (tid & 7) * 8;
        const short8 hv = *(const short8*)&Ah[row * AST + c8];
        const short8 lv = *(const short8*)&Al[row * AST + c8];
        float o[8];
        #pragma unroll
        for (int j = 0; j < 8; ++j) o[j] = bf2f((u16)hv[j]) + bf2f((u16)lv[j]);
        float4 o0 = {o[0], o[1], o[2], o[3]};
        float4 o1 = {o[4], o[5], o[6], o[7]};
        *(float4*)(Y + (size_t)(row0 + row) * 64 + c8)     = o0;
        *(float4*)(Y + (size_t)(row0 + row) * 64 + c8 + 4) = o1;
    }
}

extern "C" void kernel_launch(void* const* d_in, const int* in_sizes, int n_in,
                              void* d_out, int out_size, void* d_ws, size_t ws_size,
                              hipStream_t stream) {
    // inputs: X, U, causal_graph, W1, b1, W2, b2, W3, b3  (X never feeds the recursion)
    const float* U  = (const float*)d_in[1];
    const int*   G  = (const int*)  d_in[2];
    const float* W1 = (const float*)d_in[3];
    const float* b1 = (const float*)d_in[4];
    const float* W2 = (const float*)d_in[5];
    const float* b2 = (const float*)d_in[6];
    const float* W3 = (const float*)d_in[7];
    const float* b3 = (const float*)d_in[8];
    float* Y = (float*)d_out;

    const size_t S1 = (size_t)64 * 64 * 256;     // u16 elements per W1 array
    const size_t S2 = (size_t)64 * 256 * 128;    // u16 elements per W2 array
    u16* P1h = (u16*)d_ws;
    u16* P1l = P1h + S1;
    u16* P2h = P1l + S1;
    u16* P2l = P2h + S2;

    prep_w1<<<(64 * 64 * 256) / 256, 256, 0, stream>>>(W1, G, P1h, P1l);
    prep_w2<<<(64 * 256 * 128) / 256, 256, 0, stream>>>(W2, P2h, P2l);
    sen_fused<<<BATCH / 64, 512, 0, stream>>>(U, P1h, P1l, P2h, P2l,
                                              W1, b1, b2, W3, b3, Y);
}

// Round 4
// 556.020 us; speedup vs baseline: 1.3758x; 1.3758x over previous
//
#include <hip/hip_runtime.h>

#define BATCH 16384
#define RT    32        // batch rows per block -> 512 blocks -> 2 blocks/CU

typedef unsigned short u16;
typedef __attribute__((ext_vector_type(8))) short short8;
typedef __attribute__((ext_vector_type(4))) short short4v;
typedef __attribute__((ext_vector_type(4))) float f32x4;

// ---------- bf16 split helpers ----------
__device__ __forceinline__ u16 f2bf(float x) {
    union { float f; unsigned int u; } a; a.f = x;
    unsigned int r = a.u + 0x7fffu + ((a.u >> 16) & 1u);   // RTN-even
    return (u16)(r >> 16);
}
__device__ __forceinline__ float bf2f(u16 h) {
    union { unsigned int u; float f; } a; a.u = ((unsigned int)h) << 16;
    return a.f;
}

// ================= weight pre-pack kernels =================
// MFMA fragment pack: P[(v*KG + (k>>3))*N + n][k&7] so one fragment
// (8 consecutive k at fixed n) is a contiguous 16B load.
// W1 pre-masked by the parent mask (strictly-upper G => masked-out columns
// are exactly the not-yet-computed Y columns, so the Y tile needs no mask).
__global__ void prep_w1(const float* __restrict__ W1, const int* __restrict__ G,
                        u16* __restrict__ Ph, u16* __restrict__ Pl) {
    int idx = blockIdx.x * 256 + threadIdx.x;   // 64*64*256 exactly
    int n = idx & 255;
    int k = (idx >> 8) & 63;
    int v = idx >> 14;
    float w = (G[k * 64 + v] > 0) ? W1[((size_t)v * 65 + k) * 256 + n] : 0.0f;
    u16 h = f2bf(w);
    u16 l = f2bf(w - bf2f(h));
    size_t o = (((size_t)(v * 8 + (k >> 3)) * 256 + n) << 3) + (k & 7);
    Ph[o] = h; Pl[o] = l;
}
__global__ void prep_w2(const float* __restrict__ W2, u16* __restrict__ Ph,
                        u16* __restrict__ Pl) {
    int idx = blockIdx.x * 256 + threadIdx.x;   // 64*256*128 exactly
    int n = idx & 127;
    int k = (idx >> 7) & 255;
    int v = idx >> 15;
    float w = W2[((size_t)v * 256 + k) * 128 + n];
    u16 h = f2bf(w);
    u16 l = f2bf(w - bf2f(h));
    size_t o = (((size_t)(v * 32 + (k >> 3)) * 128 + n) << 3) + (k & 7);
    Ph[o] = h; Pl[o] = l;
}

// ================= persistent fused kernel =================
// One block = 32 batch rows, loops over all 64 variables. Y tile and h1
// live in XOR-swizzled LDS (no padding -> exactly 40 KB -> 2 blocks/CU).
// Swizzle: byte ^= (row&7)<<4  (bijective within a row's 128B/512B span,
// spreads the 16 lr-lanes' same-column reads across 8 bank groups).
__device__ __forceinline__ int a_byte(int row, int colx2) {   // A: stride 64 u16
    return (row * 128 + colx2) ^ ((row & 7) << 4);
}
__device__ __forceinline__ int h_byte(int row, int colx2) {   // h1: stride 256 u16
    return (row * 512 + colx2) ^ ((row & 7) << 4);
}

__global__ __launch_bounds__(512, 4)
void sen_fused(const float* __restrict__ U,
               const u16* __restrict__ P1h, const u16* __restrict__ P1l,
               const u16* __restrict__ P2h, const u16* __restrict__ P2l,
               const float* __restrict__ W1, const float* __restrict__ b1,
               const float* __restrict__ b2, const float* __restrict__ W3,
               const float* __restrict__ b3, float* __restrict__ Y)
{
    __shared__ __attribute__((aligned(16))) u16 Ah[RT * 64];
    __shared__ __attribute__((aligned(16))) u16 Al[RT * 64];
    __shared__ __attribute__((aligned(16))) u16 h1h[RT * 256];
    __shared__ __attribute__((aligned(16))) u16 h1l[RT * 256];

    const int tid  = threadIdx.x;
    const int row0 = blockIdx.x * RT;

    // zero Y tile (stale LDS bits could be NaN; NaN*0 = NaN in MFMA)
    {
        short8 z = {0,0,0,0,0,0,0,0};
        for (int i = tid; i < (RT * 64) / 8; i += 512) {
            *(short8*)&Ah[i * 8] = z;
            *(short8*)&Al[i * 8] = z;
        }
    }
    __syncthreads();

    const int w  = tid >> 6, l = tid & 63;
    const int lr = l & 15,  lk = l >> 4;
    const int mg = w;   // L1: dim group (32 dims each, W-dup = 1)
    const int cg = w;   // L2: col group (16 cols each, W-dup = 1)
    float* yp = (float*)h1h;   // [8][32] overlay, touched only while h1 is dead

    #pragma unroll 1
    for (int v = 0; v < 64; ++v) {
        // ---- per-step parameter prefetch (latency hides under phase-1 MFMAs) ----
        f32x4 b1v[2], w64v[2];
        #pragma unroll
        for (int ni = 0; ni < 2; ++ni) {
            b1v[ni]  = *(const f32x4*)(b1 + v * 256 + mg * 32 + ni * 16 + lk * 4);
            w64v[ni] = *(const f32x4*)(W1 + ((size_t)v * 65 + 64) * 256 + mg * 32 + ni * 16 + lk * 4);
        }
        float u_c[2];
        #pragma unroll
        for (int nj = 0; nj < 2; ++nj)
            u_c[nj] = U[(size_t)(row0 + nj * 16 + lr) * 64 + v];
        const float b2c = b2[v * 128 + cg * 16 + lr];
        const float w3c = W3[v * 128 + cg * 16 + lr];

        // ======== Phase 1 — Layer 1 (operand-swapped): h1t[dim][brow] ========
        // wave: dims mg*32..+31 (ni=2) x all 32 rows (nj=2), K=64
        f32x4 acc1[2][2];
        #pragma unroll
        for (int nj = 0; nj < 2; ++nj)
            #pragma unroll
            for (int ni = 0; ni < 2; ++ni) acc1[nj][ni] = (f32x4){0.f, 0.f, 0.f, 0.f};

        #pragma unroll
        for (int kt = 0; kt < 2; ++kt) {
            short8 Yfh[2], Yfl[2];
            #pragma unroll
            for (int nj = 0; nj < 2; ++nj) {
                const int row = nj * 16 + lr;
                const int bo  = a_byte(row, kt * 64 + lk * 16);
                Yfh[nj] = *(const short8*)&Ah[bo >> 1];
                Yfl[nj] = *(const short8*)&Al[bo >> 1];
            }
            #pragma unroll
            for (int ni = 0; ni < 2; ++ni) {
                const size_t off = (((size_t)(v * 8 + kt * 4 + lk) * 256) + mg * 32 + ni * 16 + lr) << 3;
                const short8 Wh = *(const short8*)&P1h[off];
                const short8 Wl = *(const short8*)&P1l[off];
                #pragma unroll
                for (int nj = 0; nj < 2; ++nj) {
                    acc1[nj][ni] = __builtin_amdgcn_mfma_f32_16x16x32_bf16(Wh, Yfh[nj], acc1[nj][ni], 0, 0, 0);
                    acc1[nj][ni] = __builtin_amdgcn_mfma_f32_16x16x32_bf16(Wh, Yfl[nj], acc1[nj][ni], 0, 0, 0);
                    acc1[nj][ni] = __builtin_amdgcn_mfma_f32_16x16x32_bf16(Wl, Yfh[nj], acc1[nj][ni], 0, 0, 0);
                }
            }
        }
        // epilogue: + bias + u * W1[64,:], relu, bf16 hi/lo, packed b64 stores
        #pragma unroll
        for (int nj = 0; nj < 2; ++nj) {
            const int brow = nj * 16 + lr;
            #pragma unroll
            for (int ni = 0; ni < 2; ++ni) {
                short4v ph, pl;
                #pragma unroll
                for (int r = 0; r < 4; ++r) {
                    float x = acc1[nj][ni][r] + b1v[ni][r] + u_c[nj] * w64v[ni][r];
                    x = fmaxf(x, 0.0f);
                    u16 h = f2bf(x);
                    ph[r] = (short)h;
                    pl[r] = (short)f2bf(x - bf2f(h));
                }
                const int bo = h_byte(brow, mg * 64 + ni * 32 + lk * 8);
                *(short4v*)&h1h[bo >> 1] = ph;
                *(short4v*)&h1l[bo >> 1] = pl;
            }
        }
        __syncthreads();   // B1: h1 written -> phase 2 may read

        // ======== Phase 2 — Layer 2: h2[32][cg*16..+16], K=256 ========
        f32x4 acc2[2];
        acc2[0] = (f32x4){0.f, 0.f, 0.f, 0.f};
        acc2[1] = (f32x4){0.f, 0.f, 0.f, 0.f};
        #pragma unroll
        for (int kt = 0; kt < 8; ++kt) {
            short8 Hfh[2], Hfl[2];
            #pragma unroll
            for (int mi = 0; mi < 2; ++mi) {
                const int row = mi * 16 + lr;
                const int bo  = h_byte(row, kt * 64 + lk * 16);
                Hfh[mi] = *(const short8*)&h1h[bo >> 1];
                Hfl[mi] = *(const short8*)&h1l[bo >> 1];
            }
            const size_t off = (((size_t)(v * 32 + kt * 4 + lk) * 128) + cg * 16 + lr) << 3;
            const short8 Bh = *(const short8*)&P2h[off];
            const short8 Bl = *(const short8*)&P2l[off];
            #pragma unroll
            for (int mi = 0; mi < 2; ++mi) {
                acc2[mi] = __builtin_amdgcn_mfma_f32_16x16x32_bf16(Hfh[mi], Bh, acc2[mi], 0, 0, 0);
                acc2[mi] = __builtin_amdgcn_mfma_f32_16x16x32_bf16(Hfh[mi], Bl, acc2[mi], 0, 0, 0);
                acc2[mi] = __builtin_amdgcn_mfma_f32_16x16x32_bf16(Hfl[mi], Bh, acc2[mi], 0, 0, 0);
            }
        }
        // layer 3 partials in registers (no LDS): s[mi][r] = sum over this cg's 16 cols
        float s[2][4];
        #pragma unroll
        for (int mi = 0; mi < 2; ++mi)
            #pragma unroll
            for (int r = 0; r < 4; ++r) {
                float t = fmaxf(acc2[mi][r] + b2c, 0.0f) * w3c;
                t += __shfl_xor(t, 1);
                t += __shfl_xor(t, 2);
                t += __shfl_xor(t, 4);
                t += __shfl_xor(t, 8);
                s[mi][r] = t;
            }
        __syncthreads();   // B2: all h1 reads done -> h1 region is dead

        // ======== Phase 3 — stash per-cg partials in dead h1 region ========
        if (lr == 0) {
            #pragma unroll
            for (int mi = 0; mi < 2; ++mi)
                #pragma unroll
                for (int r = 0; r < 4; ++r)
                    yp[cg * 32 + mi * 16 + lk * 4 + r] = s[mi][r];
        }
        __syncthreads();   // B3: partials visible

        // ======== Phase 4 — finalize y column into the Y tile ========
        if (tid < RT) {
            float y = b3[v];
            #pragma unroll
            for (int c = 0; c < 8; ++c) y += yp[c * 32 + tid];
            u16 h = f2bf(y);
            Ah[a_byte(tid, v * 2) >> 1] = h;
            Al[a_byte(tid, v * 2) >> 1] = f2bf(y - bf2f(h));
        }
        __syncthreads();   // B4: Y col v visible for step v+1 (h1 free again)
    }

    // ---- final coalesced store (hi+lo reconstruct), 1 float4 per thread ----
    {
        const int row = tid >> 4, c4 = (tid & 15) * 4;
        const int bo = a_byte(row, c4 * 2);
        const short4v hv = *(const short4v*)&Ah[bo >> 1];
        const short4v lv = *(const short4v*)&Al[bo >> 1];
        float4 o;
        o.x = bf2f((u16)hv[0]) + bf2f((u16)lv[0]);
        o.y = bf2f((u16)hv[1]) + bf2f((u16)lv[1]);
        o.z = bf2f((u16)hv[2]) + bf2f((u16)lv[2]);
        o.w = bf2f((u16)hv[3]) + bf2f((u16)lv[3]);
        *(float4*)(Y + (size_t)(row0 + row) * 64 + c4) = o;
    }
}

extern "C" void kernel_launch(void* const* d_in, const int* in_sizes, int n_in,
                              void* d_out, int out_size, void* d_ws, size_t ws_size,
                              hipStream_t stream) {
    // inputs: X, U, causal_graph, W1, b1, W2, b2, W3, b3  (X never feeds the recursion)
    const float* U  = (const float*)d_in[1];
    const int*   G  = (const int*)  d_in[2];
    const float* W1 = (const float*)d_in[3];
    const float* b1 = (const float*)d_in[4];
    const float* W2 = (const float*)d_in[5];
    const float* b2 = (const float*)d_in[6];
    const float* W3 = (const float*)d_in[7];
    const float* b3 = (const float*)d_in[8];
    float* Y = (float*)d_out;

    const size_t S1 = (size_t)64 * 64 * 256;     // u16 elements per W1 array
    const size_t S2 = (size_t)64 * 256 * 128;    // u16 elements per W2 array
    u16* P1h = (u16*)d_ws;
    u16* P1l = P1h + S1;
    u16* P2h = P1l + S1;
    u16* P2l = P2h + S2;

    prep_w1<<<(64 * 64 * 256) / 256, 256, 0, stream>>>(W1, G, P1h, P1l);
    prep_w2<<<(64 * 256 * 128) / 256, 256, 0, stream>>>(W2, P2h, P2l);
    sen_fused<<<BATCH / RT, 512, 0, stream>>>(U, P1h, P1l, P2h, P2l,
                                              W1, b1, b2, W3, b3, Y);
}